// Round 8
// baseline (166.015 us; speedup 1.0000x reference)
//
#include <hip/hip_runtime.h>
#include <math.h>

#define N_NODES 2048

__device__ __forceinline__ float invdeg(int j) { return j > 0 ? 1.0f / (float)j : 0.0f; }

// KA: block b owns nodes [8b, 8b+8). Computes n1 rows (via private q-prefix
// sweep over x[0,8b) + own cdiff T) and h1 rows. No cross-block sync.
__global__ __launch_bounds__(256) void k_A(const float* __restrict__ x,
                                           const float* __restrict__ cent,
                                           const float* __restrict__ Ws1,
                                           const float* __restrict__ Wn1,
                                           const float* __restrict__ b1,
                                           float* __restrict__ h1) {
  __shared__ float cs[N_NODES * 3];  // 24 KB centroids
  __shared__ float sql[32][32];      // per-chunk q sums
  __shared__ float Xs[8][32];
  __shared__ float n1t[8][36];
  __shared__ float invn_o[8];
  const int tid = threadIdx.x;
  const int b = blockIdx.x;
  const int base = b * 8;
  const int wv = tid >> 6, lane = tid & 63;

  {  // stage centroids (coalesced float4) + own x tile
    const float4* cp = (const float4*)cent;
    float4* csp = (float4*)cs;
#pragma unroll
    for (int q = 0; q < 6; ++q) csp[tid + 256 * q] = cp[tid + 256 * q];
    Xs[tid >> 5][tid & 31] = x[base * 32 + tid];
  }
  __syncthreads();

  {  // own inverse norms
    const int n = tid >> 5, f = tid & 31;
    float xv = Xs[n][f];
    float s = xv * xv;
    s += __shfl_xor(s, 1); s += __shfl_xor(s, 2); s += __shfl_xor(s, 4);
    s += __shfl_xor(s, 8); s += __shfl_xor(s, 16);
    if (f == 0) invn_o[n] = rsqrtf(s);
  }
  {  // q-sweep over [0, 8b): 32 chunks x 8 float4-lanes; on-the-fly norms
    const int c = tid >> 3, f4 = tid & 7;
    const int total = 8 * b;
    const int L = (total + 31) >> 5;
    int i0 = c * L, i1 = i0 + L;
    if (i1 > total) i1 = total;
    float4 acc = make_float4(0.f, 0.f, 0.f, 0.f);
    for (int i = i0; i < i1; ++i) {
      float4 v = ((const float4*)(x + i * 32))[f4];
      float s = v.x * v.x + v.y * v.y + v.z * v.z + v.w * v.w;
      s += __shfl_xor(s, 1); s += __shfl_xor(s, 2); s += __shfl_xor(s, 4);
      float invn = rsqrtf(s);
      acc.x += v.x * v.x * invn;
      acc.y += v.y * v.y * invn;
      acc.z += v.z * v.z * invn;
      acc.w += v.w * v.w * invn;
    }
    sql[c][f4 * 4 + 0] = acc.x;
    sql[c][f4 * 4 + 1] = acc.y;
    sql[c][f4 * 4 + 2] = acc.z;
    sql[c][f4 * 4 + 3] = acc.w;
  }
  {  // cdiff T for own nodes (wave per node, 2 rounds) -> n1t[:,32..34]
#pragma unroll
    for (int rep = 0; rep < 2; ++rep) {
      const int n = wv + 4 * rep;
      const int gn = base + n;
      const float c0 = cs[gn * 3], c1 = cs[gn * 3 + 1], c2 = cs[gn * 3 + 2];
      float s0 = 0.f, s1 = 0.f, s2 = 0.f;
      for (int i = lane; i < gn; i += 64) {
        float a0 = cs[i * 3], a1 = cs[i * 3 + 1], a2 = cs[i * 3 + 2];
        s0 += a0 * fabsf(a0 - c0);
        s1 += a1 * fabsf(a1 - c1);
        s2 += a2 * fabsf(a2 - c2);
      }
#pragma unroll
      for (int d = 32; d > 0; d >>= 1) {
        s0 += __shfl_down(s0, d);
        s1 += __shfl_down(s1, d);
        s2 += __shfl_down(s2, d);
      }
      if (lane == 0) {
        float g = invdeg(gn);
        n1t[n][32] = s0 * g;
        n1t[n][33] = s1 * g;
        n1t[n][34] = s2 * g;
      }
    }
  }
  __syncthreads();

  if (tid < 32) {  // combine chunk sums, run prefix through own 8 nodes
    const int f = tid;
    float run = 0.f;
#pragma unroll
    for (int c = 0; c < 32; ++c) run += sql[c][f];
#pragma unroll
    for (int k = 0; k < 8; ++k) {
      float xv = Xs[k][f];
      float inz = invn_o[k];
      n1t[k][f] = run * xv * inz * invdeg(base + k);
      run += xv * xv * inz;
    }
  }
  __syncthreads();

  {  // h1 rows (verified R7-S4 pattern)
    const int o = tid & 63, nh = tid >> 6;
    float acc0 = b1[o], acc1 = b1[o];
#pragma unroll
    for (int f = 0; f < 32; ++f) {
      float ws = Ws1[f * 64 + o], wn = Wn1[f * 64 + o];
      acc0 += Xs[nh][f] * ws + n1t[nh][f] * wn;
      acc1 += Xs[nh + 4][f] * ws + n1t[nh + 4][f] * wn;
    }
#pragma unroll
    for (int f = 32; f < 35; ++f) {
      float ws = Ws1[f * 64 + o], wn = Wn1[f * 64 + o];
      acc0 += cs[(base + nh) * 3 + (f - 32)] * ws + n1t[nh][f] * wn;
      acc1 += cs[(base + nh + 4) * 3 + (f - 32)] * ws + n1t[nh + 4][f] * wn;
    }
    h1[(base + nh) * 64 + o] = acc0;
    h1[(base + nh + 4) * 64 + o] = acc1;
  }
}

// K34: block b owns nodes [8b, 8b+8). Redundant column-sum of h1[0,8b)
// -> n2 -> h2 -> A/B rows. No cross-block sync.
__global__ __launch_bounds__(256) void k_n2AB(const float* __restrict__ h1,
                                              const float* __restrict__ Ws2,
                                              const float* __restrict__ Wn2,
                                              const float* __restrict__ b2,
                                              const float* __restrict__ Wm1,
                                              const float* __restrict__ bm1,
                                              float* __restrict__ A,
                                              float* __restrict__ Bm) {
  __shared__ float part[16][64];
  __shared__ float n2t[8][64];
  __shared__ float h2t[8][32];
  const int tid = threadIdx.x;
  const int b = blockIdx.x;
  const int base = b * 8;
  {  // 16 chunks x 16 float4 col-groups, coalesced
    const int c = tid >> 4, o4 = tid & 15;
    const int total = 8 * b;
    const int L = (total + 15) >> 4;
    int i0 = c * L, i1 = i0 + L;
    if (i1 > total) i1 = total;
    float4 acc = make_float4(0.f, 0.f, 0.f, 0.f);
    for (int i = i0; i < i1; ++i) {
      float4 v = ((const float4*)(h1 + i * 64))[o4];
      acc.x += v.x; acc.y += v.y; acc.z += v.z; acc.w += v.w;
    }
    part[c][o4 * 4 + 0] = acc.x;
    part[c][o4 * 4 + 1] = acc.y;
    part[c][o4 * 4 + 2] = acc.z;
    part[c][o4 * 4 + 3] = acc.w;
  }
  __syncthreads();
  if (tid < 64) {
    float run = 0.f;
#pragma unroll
    for (int c = 0; c < 16; ++c) run += part[c][tid];
#pragma unroll
    for (int k = 0; k < 8; ++k) {
      n2t[k][tid] = run * invdeg(base + k);
      run += h1[(base + k) * 64 + tid];
    }
  }
  __syncthreads();
  {  // h2 (verified R3-K4 body)
    const int g = tid & 31, n = tid >> 5;
    const int gn = base + n;
    float acc = b2[g];
#pragma unroll
    for (int f = 0; f < 64; ++f)
      acc += h1[gn * 64 + f] * Ws2[f * 32 + g] + n2t[n][f] * Wn2[f * 32 + g];
    h2t[n][g] = acc;
  }
  __syncthreads();
  {
    const int g = tid & 31, n = tid >> 5;
    float a = 0.f, bb = bm1[g];
#pragma unroll
    for (int f = 0; f < 32; ++f) {
      float v = h2t[n][f];
      a += v * Wm1[f * 32 + g];
      bb += v * Wm1[(32 + f) * 32 + g];
    }
    A[(base + n) * 32 + g] = a;
    Bm[(base + n) * 32 + g] = bb;
  }
}

// K5: per-edge head (unchanged verified R3 kernel).
__global__ __launch_bounds__(256) void k_edges(const float* __restrict__ A,
                                               const float* __restrict__ Bm,
                                               const float* __restrict__ Wm2,
                                               const float* __restrict__ bm2,
                                               float2* __restrict__ out) {
  const int tid = threadIdx.x;
  const int j0 = blockIdx.x * 256;
  const int i0 = blockIdx.y * 8;
  if (i0 >= j0 + 255) return;
  const int j = j0 + tid;
  float Br[32];
  const float4* bp = (const float4*)(Bm + j * 32);
#pragma unroll
  for (int q = 0; q < 8; ++q) {
    float4 v = bp[q];
    Br[4 * q + 0] = v.x;
    Br[4 * q + 1] = v.y;
    Br[4 * q + 2] = v.z;
    Br[4 * q + 3] = v.w;
  }
  float wd[32];
#pragma unroll
  for (int f = 0; f < 32; ++f) wd[f] = Wm2[f * 2 + 1] - Wm2[f * 2];
  const float db = bm2[1] - bm2[0];
#pragma unroll
  for (int ii = 0; ii < 8; ++ii) {
    const int i = i0 + ii;
    const float* Ar = A + i * 32;  // wave-uniform -> scalar loads
    float d = db;
#pragma unroll
    for (int f = 0; f < 32; ++f)
      d += fmaxf(Ar[f] + Br[f], 0.f) * wd[f];
    if (i < j) {
      float p0 = 1.0f / (1.0f + __expf(d));
      int e = i * (2 * N_NODES - 1 - i) / 2 + (j - i - 1);
      out[e] = make_float2(p0, 1.0f - p0);
    }
  }
}

extern "C" void kernel_launch(void* const* d_in, const int* in_sizes, int n_in,
                              void* d_out, int out_size, void* d_ws, size_t ws_size,
                              hipStream_t stream) {
  const float* x    = (const float*)d_in[0];
  const float* cent = (const float*)d_in[1];
  const float* Ws1  = (const float*)d_in[2];
  const float* Wn1  = (const float*)d_in[3];
  const float* b1   = (const float*)d_in[4];
  const float* Ws2  = (const float*)d_in[5];
  const float* Wn2  = (const float*)d_in[6];
  const float* b2   = (const float*)d_in[7];
  const float* Wm1  = (const float*)d_in[8];
  const float* bm1  = (const float*)d_in[9];
  const float* Wm2  = (const float*)d_in[10];
  const float* bm2  = (const float*)d_in[11];

  float* h1 = (float*)d_ws;           // 2048*64
  float* A  = h1 + 2048 * 64;         // 2048*32
  float* Bm = A + 2048 * 32;          // 2048*32

  k_A<<<256, 256, 0, stream>>>(x, cent, Ws1, Wn1, b1, h1);
  k_n2AB<<<256, 256, 0, stream>>>(h1, Ws2, Wn2, b2, Wm1, bm1, A, Bm);
  k_edges<<<dim3(8, 256), 256, 0, stream>>>(A, Bm, Wm2, bm2, (float2*)d_out);
}